// Round 15
// baseline (579.571 us; speedup 1.0000x reference)
//
#include <hip/hip_runtime.h>
#include <hip/hip_bf16.h>

constexpr int TN = 100000;   // nodes
constexpr int TE = 200000;   // edges
constexpr int TG = 4000;     // graphs
constexpr int TH = 128;      // hidden

using short8 = __attribute__((ext_vector_type(8))) short;
using f32x4  = __attribute__((ext_vector_type(4))) float;
typedef __hip_bfloat16 bf16;

#define DEVINL __device__ __forceinline__
DEVINL float sigm(float x)  { return 1.f / (1.f + __expf(-x)); }
DEVINL float ftanh(float x) { return 1.f - 2.f / (__expf(2.f * x) + 1.f); }
DEVINL void unpack8(uint4 v, float* f) {
    const ushort* u = (const ushort*)&v;
#pragma unroll
    for (int j = 0; j < 8; ++j) f[j] = __bfloat162float(*(const bf16*)&u[j]);
}

// ================= merged weight conversion =================
__global__ void convAll(const float* __restrict__ g1, const float* __restrict__ g2,
                        const float* __restrict__ e1, const float* __restrict__ e2,
                        const float* __restrict__ gwih, const float* __restrict__ gwhh,
                        const float* __restrict__ lwih, const float* __restrict__ lwhh,
                        bf16* __restrict__ w6, bf16* __restrict__ wgru,
                        bf16* __restrict__ wl) {
    int i = blockIdx.x * 256 + threadIdx.x;
    if (i < 6 * TH * TH) {
        int m = i >> 14, r = i & 16383;
        int n = r >> 7, k = r & 127;
        const float* s = (m == 0) ? g1 : (m == 1) ? g1 + TH * TH
                       : (m == 2) ? g2 : (m == 3) ? g2 + TH * TH
                       : (m == 4) ? e1 : e2;
        w6[i] = __float2bfloat16(s[k * TH + n]);
        return;
    }
    i -= 6 * TH * TH;
    if (i < 2 * 384 * TH) {
        const float* s = (i < 384 * TH) ? gwih : gwhh;
        int r = (i < 384 * TH) ? i : i - 384 * TH;
        wgru[i] = __float2bfloat16(s[r]);
        return;
    }
    i -= 2 * 384 * TH;
    if (i < 512 * 256) {
        int c = i >> 8, k = i & 255;
        float v = (k < 128) ? lwih[c * 256 + k] + lwhh[c * 128 + k] : lwih[c * 256 + k];
        wl[i] = __float2bfloat16(v);
    }
}

// ================= node projection: 64 rows/block ============
template<int K>
__global__ __launch_bounds__(256) void proj64(const float* __restrict__ X,
                                              const float* __restrict__ W,
                                              const float* __restrict__ b,
                                              ushort* __restrict__ out, int M) {
    __shared__ float xs[64][K];
    int tid = threadIdx.x;
    int bm = blockIdx.x * 64;
    for (int i = tid; i < 64 * K; i += 256) {
        int r = i / K, k = i % K;
        xs[r][k] = (bm + r < M) ? X[(size_t)(bm + r) * K + k] : 0.f;
    }
    __syncthreads();
    int rb = tid >> 4, h0 = (tid & 15) * 8;
    float acc[4][8];
#pragma unroll
    for (int j = 0; j < 4; ++j)
#pragma unroll
        for (int c = 0; c < 8; ++c) acc[j][c] = b[h0 + c];
#pragma unroll
    for (int k = 0; k < K; ++k) {
        float4 w0 = *(const float4*)(W + k * TH + h0);
        float4 w1 = *(const float4*)(W + k * TH + h0 + 4);
#pragma unroll
        for (int j = 0; j < 4; ++j) {
            float xv = xs[rb + 16 * j][k];
            acc[j][0] = fmaf(xv, w0.x, acc[j][0]); acc[j][1] = fmaf(xv, w0.y, acc[j][1]);
            acc[j][2] = fmaf(xv, w0.z, acc[j][2]); acc[j][3] = fmaf(xv, w0.w, acc[j][3]);
            acc[j][4] = fmaf(xv, w1.x, acc[j][4]); acc[j][5] = fmaf(xv, w1.y, acc[j][5]);
            acc[j][6] = fmaf(xv, w1.z, acc[j][6]); acc[j][7] = fmaf(xv, w1.w, acc[j][7]);
        }
    }
#pragma unroll
    for (int j = 0; j < 4; ++j) {
        int row = bm + rb + 16 * j;
        if (row >= M) continue;
        ushort o[8];
#pragma unroll
        for (int c = 0; c < 8; ++c) {
            bf16 v = __float2bfloat16(acc[j][c]);
            o[c] = *(ushort*)&v;
        }
        *(uint4*)(out + (size_t)row * TH + h0) = *(uint4*)o;
    }
}

// ===== proj_gather: e0[slot] = proj(edge_attr[einv[slot]]) — coalesced writes =====
__global__ __launch_bounds__(256) void proj_gather(
    const float* __restrict__ edge_attr, const float* __restrict__ W,
    const float* __restrict__ b, const int* __restrict__ einv,
    ushort* __restrict__ out, int M) {
    __shared__ float xs[64][4];
    int tid = threadIdx.x;
    int bm = blockIdx.x * 64;
    if (tid < 64) {
        float4 a = make_float4(0.f, 0.f, 0.f, 0.f);
        if (bm + tid < M) a = *(const float4*)(edge_attr + (size_t)einv[bm + tid] * 4);
        xs[tid][0] = a.x; xs[tid][1] = a.y; xs[tid][2] = a.z; xs[tid][3] = a.w;
    }
    __syncthreads();
    int rb = tid >> 4, h0 = (tid & 15) * 8;
    float acc[4][8];
#pragma unroll
    for (int j = 0; j < 4; ++j)
#pragma unroll
        for (int c = 0; c < 8; ++c) acc[j][c] = b[h0 + c];
#pragma unroll
    for (int k = 0; k < 4; ++k) {
        float4 w0 = *(const float4*)(W + k * TH + h0);
        float4 w1 = *(const float4*)(W + k * TH + h0 + 4);
#pragma unroll
        for (int j = 0; j < 4; ++j) {
            float xv = xs[rb + 16 * j][k];
            acc[j][0] = fmaf(xv, w0.x, acc[j][0]); acc[j][1] = fmaf(xv, w0.y, acc[j][1]);
            acc[j][2] = fmaf(xv, w0.z, acc[j][2]); acc[j][3] = fmaf(xv, w0.w, acc[j][3]);
            acc[j][4] = fmaf(xv, w1.x, acc[j][4]); acc[j][5] = fmaf(xv, w1.y, acc[j][5]);
            acc[j][6] = fmaf(xv, w1.z, acc[j][6]); acc[j][7] = fmaf(xv, w1.w, acc[j][7]);
        }
    }
#pragma unroll
    for (int j = 0; j < 4; ++j) {
        int row = bm + rb + 16 * j;
        if (row >= M) continue;
        ushort o[8];
#pragma unroll
        for (int c = 0; c < 8; ++c) {
            bf16 v = __float2bfloat16(acc[j][c]);
            o[c] = *(ushort*)&v;
        }
        *(uint4*)(out + (size_t)row * TH + h0) = *(uint4*)o;
    }
}

// ================= CSR build =================
__global__ void count_deg(const int* __restrict__ ei_dst, int* __restrict__ deg, int En) {
    int e = blockIdx.x * 256 + threadIdx.x;
    if (e < En) atomicAdd(&deg[ei_dst[e]], 1);
}
__global__ void scan_block(const int* __restrict__ deg, int* __restrict__ rowptr,
                           int* __restrict__ bsum, int Nn) {
    __shared__ int sm[256];
    int tid = threadIdx.x;
    int gid = blockIdx.x * 256 + tid;
    int v = (gid < Nn) ? deg[gid] : 0;
    int x = v;
    sm[tid] = x; __syncthreads();
    for (int off = 1; off < 256; off <<= 1) {
        int t = (tid >= off) ? sm[tid - off] : 0;
        __syncthreads();
        x += t; sm[tid] = x;
        __syncthreads();
    }
    if (gid < Nn) rowptr[gid] = x - v;
    if (tid == 255) bsum[blockIdx.x] = x;
}
__global__ void scan_bsum(const int* __restrict__ bsum, int* __restrict__ bsumx, int nb) {
    __shared__ int sm[512];
    int tid = threadIdx.x;
    int v = (tid < nb) ? bsum[tid] : 0;
    int x = v;
    sm[tid] = x; __syncthreads();
    for (int off = 1; off < 512; off <<= 1) {
        int t = (tid >= off) ? sm[tid - off] : 0;
        __syncthreads();
        x += t; sm[tid] = x;
        __syncthreads();
    }
    if (tid < nb) bsumx[tid] = x - v;
}
__global__ void add_off(int* __restrict__ rowptr, const int* __restrict__ bsumx,
                        int Nn, int Etot) {
    int gid = blockIdx.x * 256 + threadIdx.x;
    if (gid < Nn) rowptr[gid] += bsumx[gid >> 8];
    if (gid == 0) rowptr[Nn] = Etot;
}
__global__ void fill_csr(const int* __restrict__ ei_src, const int* __restrict__ ei_dst,
                         const int* __restrict__ rowptr, int* __restrict__ cur,
                         int* __restrict__ srcp, int* __restrict__ einv, int En) {
    int e = blockIdx.x * 256 + threadIdx.x;
    if (e >= En) return;
    int d = ei_dst[e];
    int p = atomicAdd(&cur[d], 1);
    int slot = rowptr[d] + p;
    srcp[slot] = ei_src[e];
    einv[slot] = e;
}
__global__ void build_gptr(const int* __restrict__ batch, int* __restrict__ gptr,
                           int Nn, int Gn) {
    int n = blockIdx.x * 256 + threadIdx.x;
    if (n >= Nn) return;
    int bc = batch[n];
    int bp = (n == 0) ? -1 : batch[n - 1];
    for (int g = bp + 1; g <= bc; ++g) gptr[g] = n;
    if (n == Nn - 1) for (int g = bc + 1; g <= Gn; ++g) gptr[g] = Nn;
}

// ========== aggregation, 16 threads/node, 8 ch/thread, 2-way unroll ==========
__global__ __launch_bounds__(256) void aggregate_v8(
    const ushort* __restrict__ node, const ushort* __restrict__ ef,
    const int* __restrict__ srcp, const int* __restrict__ rowptr,
    const float* __restrict__ eps, int l, ushort* __restrict__ zb, int Nn) {
    int t = blockIdx.x * 256 + threadIdx.x;
    int n = t >> 4;
    if (n >= Nn) return;
    int c8 = (t & 15) * 8;
    float se = 1.f + eps[l];
    float acc[8];
    uint4 nv = *(const uint4*)(node + (size_t)n * TH + c8);
    unpack8(nv, acc);
#pragma unroll
    for (int j = 0; j < 8; ++j) acc[j] *= se;
    int s0 = rowptr[n], s1 = rowptr[n + 1];
    int i = s0;
    for (; i + 1 < s1; i += 2) {
        int sa = srcp[i], sb = srcp[i + 1];
        uint4 av0 = *(const uint4*)(node + (size_t)sa * TH + c8);
        uint4 bv0 = *(const uint4*)(ef + (size_t)i * TH + c8);
        uint4 av1 = *(const uint4*)(node + (size_t)sb * TH + c8);
        uint4 bv1 = *(const uint4*)(ef + (size_t)(i + 1) * TH + c8);
        float a0[8], b0[8], a1[8], b1[8];
        unpack8(av0, a0); unpack8(bv0, b0);
        unpack8(av1, a1); unpack8(bv1, b1);
#pragma unroll
        for (int j = 0; j < 8; ++j)
            acc[j] += fmaxf(a0[j] + b0[j], 0.f) + fmaxf(a1[j] + b1[j], 0.f);
    }
    if (i < s1) {
        int sa = srcp[i];
        uint4 av = *(const uint4*)(node + (size_t)sa * TH + c8);
        uint4 bv = *(const uint4*)(ef + (size_t)i * TH + c8);
        float af[8], bf[8];
        unpack8(av, af); unpack8(bv, bf);
#pragma unroll
        for (int j = 0; j < 8; ++j) acc[j] += fmaxf(af[j] + bf[j], 0.f);
    }
    ushort o[8];
#pragma unroll
    for (int j = 0; j < 8; ++j) {
        bf16 v = __float2bfloat16(acc[j]);
        o[j] = *(ushort*)&v;
    }
    *(uint4*)(zb + (size_t)n * TH + c8) = *(uint4*)o;
}

// ================= fused 2-layer MLP (weights preloaded to registers) =================
__global__ __launch_bounds__(256) void mlp2_fused(
    const ushort* __restrict__ A, const ushort* __restrict__ W1t,
    const float* __restrict__ b1, const ushort* __restrict__ W2t,
    const float* __restrict__ b2, ushort* __restrict__ C, int M)
{
    __shared__ ushort As[128 * 128];
    __shared__ ushort Ts[128 * 128];
    const int tid = threadIdx.x;
    const int bm = blockIdx.x * 128;
    const int lane = tid & 63, w = tid >> 6;
    const int lr = lane & 15, lq = lane >> 4;
    const int wm = (w & 1) * 64, wn = (w >> 1) * 64;
    short8 wf[4][4];
#pragma unroll
    for (int ni = 0; ni < 4; ++ni)
#pragma unroll
        for (int ks = 0; ks < 4; ++ks)
            wf[ni][ks] = *(const short8*)(W1t + (size_t)(wn + ni * 16 + lr) * 128 + ks * 32 + lq * 8);
#pragma unroll
    for (int p = 0; p < 8; ++p) {
        int ch = p * 256 + tid;
        int r = ch >> 4, c = ch & 15;
        int row = bm + r;
        uint4 v = make_uint4(0u, 0u, 0u, 0u);
        if (row < M) v = *(const uint4*)(A + (size_t)row * 128 + c * 8);
        *(uint4*)(&As[r * 128 + ((c ^ (r & 15)) * 8)]) = v;
    }
    __syncthreads();
    {
        f32x4 acc[4][4] = {};
#pragma unroll
        for (int ks = 0; ks < 4; ++ks) {
            int cb = ks * 4 + lq;
            short8 af[4];
#pragma unroll
            for (int mi = 0; mi < 4; ++mi)
                af[mi] = *(const short8*)(&As[(wm + mi * 16 + lr) * 128 + ((cb ^ lr) * 8)]);
#pragma unroll
            for (int mi = 0; mi < 4; ++mi)
#pragma unroll
                for (int ni = 0; ni < 4; ++ni)
                    acc[mi][ni] = __builtin_amdgcn_mfma_f32_16x16x32_bf16(af[mi], wf[ni][ks], acc[mi][ni], 0, 0, 0);
        }
#pragma unroll
        for (int mi = 0; mi < 4; ++mi)
#pragma unroll
            for (int reg = 0; reg < 4; ++reg) {
                int row = wm + mi * 16 + lq * 4 + reg;
#pragma unroll
                for (int ni = 0; ni < 4; ++ni) {
                    int col = wn + ni * 16 + lr;
                    float v = fmaxf(acc[mi][ni][reg] + b1[col], 0.f);
                    bf16 bv = __float2bfloat16(v);
                    Ts[row * 128 + (((col >> 3) ^ (row & 15)) * 8) + (col & 7)] = *(ushort*)&bv;
                }
            }
    }
#pragma unroll
    for (int ni = 0; ni < 4; ++ni)
#pragma unroll
        for (int ks = 0; ks < 4; ++ks)
            wf[ni][ks] = *(const short8*)(W2t + (size_t)(wn + ni * 16 + lr) * 128 + ks * 32 + lq * 8);
    __syncthreads();
    {
        f32x4 acc[4][4] = {};
#pragma unroll
        for (int ks = 0; ks < 4; ++ks) {
            int cb = ks * 4 + lq;
            short8 af[4];
#pragma unroll
            for (int mi = 0; mi < 4; ++mi)
                af[mi] = *(const short8*)(&Ts[(wm + mi * 16 + lr) * 128 + ((cb ^ lr) * 8)]);
#pragma unroll
            for (int mi = 0; mi < 4; ++mi)
#pragma unroll
                for (int ni = 0; ni < 4; ++ni)
                    acc[mi][ni] = __builtin_amdgcn_mfma_f32_16x16x32_bf16(af[mi], wf[ni][ks], acc[mi][ni], 0, 0, 0);
        }
#pragma unroll
        for (int mi = 0; mi < 4; ++mi)
#pragma unroll
            for (int reg = 0; reg < 4; ++reg) {
                int row = bm + wm + mi * 16 + lq * 4 + reg;
                if (row >= M) continue;
#pragma unroll
                for (int ni = 0; ni < 4; ++ni) {
                    int col = wn + ni * 16 + lr;
                    bf16 bv = __float2bfloat16(acc[mi][ni][reg] + b2[col]);
                    C[(size_t)row * 128 + col] = *(ushort*)&bv;
                }
            }
    }
}

// ===== fused GRU: 512 thr, 64 rows/block, 16 cols/wave, 96 MFMA/wave =====
__global__ __launch_bounds__(512, 4) void gru_fused(
    const ushort* __restrict__ mfeat, const ushort* __restrict__ wih,
    const ushort* __restrict__ whh, const float* __restrict__ bih,
    const float* __restrict__ bhh, ushort* __restrict__ node, int Nn)
{
    __shared__ ushort Ms[64 * 128];
    __shared__ ushort Hs[64 * 128];
    const int tid = threadIdx.x;
    const int bm = blockIdx.x * 64;
#pragma unroll
    for (int p = 0; p < 4; ++p) {
        int ch = p * 512 + tid;
        bool isH = ch >= 1024;
        int r = (ch >> 4) & 63, c = ch & 15;
        int row = bm + r;
        uint4 v = make_uint4(0u, 0u, 0u, 0u);
        if (row < Nn) v = *(const uint4*)((isH ? node : mfeat) + (size_t)row * 128 + c * 8);
        ushort* dst = isH ? Hs : Ms;
        *(uint4*)(&dst[r * 128 + ((c ^ (r & 15)) * 8)]) = v;
    }
    __syncthreads();
    const int lane = tid & 63, w = tid >> 6;
    const int lr = lane & 15, lq = lane >> 4;
    const int col = w * 16 + lr;
    f32x4 aR[4] = {}, aZ[4] = {}, aN[4] = {}, aH[4] = {};
#pragma unroll
    for (int ks = 0; ks < 4; ++ks) {
        int koff = ks * 32 + lq * 8;
        short8 wv0 = *(const short8*)(wih + (size_t)col * 128 + koff);
        short8 wv1 = *(const short8*)(wih + (size_t)(128 + col) * 128 + koff);
        short8 wv2 = *(const short8*)(wih + (size_t)(256 + col) * 128 + koff);
        short8 wv3 = *(const short8*)(whh + (size_t)col * 128 + koff);
        short8 wv4 = *(const short8*)(whh + (size_t)(128 + col) * 128 + koff);
        short8 wv5 = *(const short8*)(whh + (size_t)(256 + col) * 128 + koff);
        int cb = ks * 4 + lq;
#pragma unroll
        for (int rt = 0; rt < 4; ++rt) {
            int off = (rt * 16 + lr) * 128 + ((cb ^ lr) * 8);
            short8 am = *(const short8*)(&Ms[off]);
            short8 ah = *(const short8*)(&Hs[off]);
            aR[rt] = __builtin_amdgcn_mfma_f32_16x16x32_bf16(am, wv0, aR[rt], 0, 0, 0);
            aR[rt] = __builtin_amdgcn_mfma_f32_16x16x32_bf16(ah, wv3, aR[rt], 0, 0, 0);
            aZ[rt] = __builtin_amdgcn_mfma_f32_16x16x32_bf16(am, wv1, aZ[rt], 0, 0, 0);
            aZ[rt] = __builtin_amdgcn_mfma_f32_16x16x32_bf16(ah, wv4, aZ[rt], 0, 0, 0);
            aN[rt] = __builtin_amdgcn_mfma_f32_16x16x32_bf16(am, wv2, aN[rt], 0, 0, 0);
            aH[rt] = __builtin_amdgcn_mfma_f32_16x16x32_bf16(ah, wv5, aH[rt], 0, 0, 0);
        }
    }
    {
        int h = col;
        float br = bih[h] + bhh[h];
        float bz = bih[128 + h] + bhh[128 + h];
        float bin = bih[256 + h], bhn = bhh[256 + h];
#pragma unroll
        for (int rt = 0; rt < 4; ++rt)
#pragma unroll
            for (int reg = 0; reg < 4; ++reg) {
                int lrow = rt * 16 + lq * 4 + reg;
                int row = bm + lrow;
                if (row >= Nn) continue;
                float r = sigm(aR[rt][reg] + br);
                float z = sigm(aZ[rt][reg] + bz);
                float n = ftanh(aN[rt][reg] + bin + r * (aH[rt][reg] + bhn));
                int hofs = lrow * 128 + (((h >> 3) ^ (lrow & 15)) * 8) + (h & 7);
                float hold = __bfloat162float(*(const bf16*)&Hs[hofs]);
                bf16 hv = __float2bfloat16((1.f - z) * n + z * hold);
                node[(size_t)row * 128 + h] = *(ushort*)&hv;
            }
    }
}

// ================= fused LSTM step (16 graphs/block) =================
__global__ __launch_bounds__(256) void lstm_fused(
    ushort* __restrict__ s, const ushort* __restrict__ Wl,
    const float* __restrict__ bih, const float* __restrict__ bhh,
    float* __restrict__ cl, int Gn)
{
    __shared__ ushort Ss[16 * 256];
    const int tid = threadIdx.x;
    const int bm = blockIdx.x * 16;
#pragma unroll
    for (int p = 0; p < 2; ++p) {
        int ch = p * 256 + tid;
        int r = ch >> 5, c = ch & 31;
        int row = bm + r;
        uint4 v = make_uint4(0u, 0u, 0u, 0u);
        if (row < Gn) v = *(const uint4*)(s + (size_t)row * 256 + c * 8);
        *(uint4*)(&Ss[r * 256 + ((c ^ (r & 15)) * 8)]) = v;
    }
    __syncthreads();
    const int lane = tid & 63, w = tid >> 6;
    const int lr = lane & 15, lq = lane >> 4;
    f32x4 acc[4][2] = {};
#pragma unroll
    for (int ks = 0; ks < 8; ++ks) {
        int cb = ks * 4 + lq;
        short8 am = *(const short8*)(&Ss[lr * 256 + ((cb ^ lr) * 8)]);
        int koff = ks * 32 + lq * 8;
#pragma unroll
        for (int g = 0; g < 4; ++g)
#pragma unroll
            for (int sub = 0; sub < 2; ++sub) {
                int col = g * 128 + w * 32 + sub * 16 + lr;
                short8 bf = *(const short8*)(Wl + (size_t)col * 256 + koff);
                acc[g][sub] = __builtin_amdgcn_mfma_f32_16x16x32_bf16(am, bf, acc[g][sub], 0, 0, 0);
            }
    }
#pragma unroll
    for (int sub = 0; sub < 2; ++sub) {
        int h = w * 32 + sub * 16 + lr;
        float bi = bih[h] + bhh[h];
        float bff = bih[128 + h] + bhh[128 + h];
        float bg = bih[256 + h] + bhh[256 + h];
        float bo = bih[384 + h] + bhh[384 + h];
#pragma unroll
        for (int reg = 0; reg < 4; ++reg) {
            int row = bm + lq * 4 + reg;
            if (row >= Gn) continue;
            float iv = sigm(acc[0][sub][reg] + bi);
            float fv = sigm(acc[1][sub][reg] + bff);
            float gv = ftanh(acc[2][sub][reg] + bg);
            float ov = sigm(acc[3][sub][reg] + bo);
            float c = fv * cl[(size_t)row * 128 + h] + iv * gv;
            cl[(size_t)row * 128 + h] = c;
            bf16 hv = __float2bfloat16(ov * ftanh(c));
            s[(size_t)row * 256 + h] = *(ushort*)&hv;
        }
    }
}

// ========== fused per-graph attention (register-cached node rows) ==========
__global__ __launch_bounds__(256) void att_fused(
    const ushort* __restrict__ node, ushort* __restrict__ s,
    const int* __restrict__ gptr)
{
    __shared__ float q[128];
    __shared__ float es[512];
    __shared__ float red[8];
    __shared__ float part[16][128];
    int g = blockIdx.x;
    int tid = threadIdx.x, lane = tid & 63, wid = tid >> 6;
    int n0 = gptr[g], n1 = gptr[g + 1];
    int cnt = n1 - n0; if (cnt > 512) cnt = 512;
    if (tid < 128) q[tid] = __bfloat162float(((const bf16*)s)[(size_t)g * 256 + tid]);
    __syncthreads();
    int gr = tid >> 4, c8 = (tid & 15) * 8;
    // dot pass — cache this thread's first 8 row-chunks in registers
    uint4 vc[8];
    for (int i0 = 0; i0 < cnt; i0 += 16) {
        int i = i0 + gr;
        float p = 0.f;
        if (i < cnt) {
            uint4 v = *(const uint4*)(node + (size_t)(n0 + i) * TH + c8);
            int it = i0 >> 4;
            if (it < 8) vc[it] = v;
            float f[8]; unpack8(v, f);
#pragma unroll
            for (int j = 0; j < 8; ++j) p = fmaf(f[j], q[c8 + j], p);
        }
        p += __shfl_down(p, 8, 16);
        p += __shfl_down(p, 4, 16);
        p += __shfl_down(p, 2, 16);
        p += __shfl_down(p, 1, 16);
        if ((tid & 15) == 0 && i < cnt) es[i] = p;
    }
    __syncthreads();
    float m = -1e30f;
    for (int i = tid; i < cnt; i += 256) m = fmaxf(m, es[i]);
    for (int off = 32; off; off >>= 1) m = fmaxf(m, __shfl_down(m, off));
    if (lane == 0) red[wid] = m;
    __syncthreads();
    m = fmaxf(fmaxf(red[0], red[1]), fmaxf(red[2], red[3]));
    float sm = 0.f;
    for (int i = tid; i < cnt; i += 256) { float ex = __expf(es[i] - m); es[i] = ex; sm += ex; }
    for (int off = 32; off; off >>= 1) sm += __shfl_down(sm, off);
    if (lane == 0) red[4 + wid] = sm;
    __syncthreads();
    sm = red[4] + red[5] + red[6] + red[7];
    float inv = 1.f / fmaxf(sm, 1e-9f);
    // weighted sum — replay cached rows, fall back to global past 128 nodes
    float racc[8] = {};
    for (int i = gr; i < cnt; i += 16) {
        int it = i >> 4;
        uint4 v = (it < 8) ? vc[it]
                           : *(const uint4*)(node + (size_t)(n0 + i) * TH + c8);
        float f[8]; unpack8(v, f);
        float a = es[i];
#pragma unroll
        for (int j = 0; j < 8; ++j) racc[j] = fmaf(a, f[j], racc[j]);
    }
#pragma unroll
    for (int j = 0; j < 8; ++j) part[gr][c8 + j] = racc[j];
    __syncthreads();
    if (tid < 128) {
        float r = 0.f;
#pragma unroll
        for (int k = 0; k < 16; ++k) r += part[k][tid];
        bf16 rv = __float2bfloat16(r * inv);
        s[(size_t)g * 256 + 128 + tid] = *(ushort*)&rv;
    }
}

// ================= final FC =================
__global__ __launch_bounds__(128) void final_fc(const ushort* __restrict__ s,
                                                const float* __restrict__ w1,
                                                const float* __restrict__ b1,
                                                const float* __restrict__ w2,
                                                const float* __restrict__ b2,
                                                float* __restrict__ out) {
    __shared__ float q[256];
    __shared__ float red[2];
    int g = blockIdx.x, t = threadIdx.x;
    q[t] = __bfloat162float(((const bf16*)s)[(size_t)g * 256 + t]);
    q[t + 128] = __bfloat162float(((const bf16*)s)[(size_t)g * 256 + 128 + t]);
    __syncthreads();
    float acc = b1[t];
    for (int k = 0; k < 256; ++k) acc = fmaf(q[k], w1[k * TH + t], acc);
    acc = fmaxf(acc, 0.f);
    float p = acc * w2[t];
    for (int off = 32; off; off >>= 1) p += __shfl_down(p, off);
    if ((t & 63) == 0) red[t >> 6] = p;
    __syncthreads();
    if (t == 0) out[g] = red[0] + red[1] + b2[0];
}

// ---------------------------------------------------------------------------
static void launch_mlp2(const void* A, const bf16* W1t, const float* b1,
                        const bf16* W2t, const float* b2, void* C, int M, hipStream_t s) {
    hipLaunchKernelGGL(mlp2_fused, dim3((M + 127) / 128), dim3(256), 0, s,
                       (const ushort*)A, (const ushort*)W1t, b1, (const ushort*)W2t, b2,
                       (ushort*)C, M);
}

extern "C" void kernel_launch(void* const* d_in, const int* in_sizes, int n_in,
                              void* d_out, int out_size, void* d_ws, size_t ws_size,
                              hipStream_t stream) {
    const float* x         = (const float*)d_in[0];
    const float* edge_attr = (const float*)d_in[1];
    const int*   edge_index= (const int*)d_in[2];
    const int*   batch     = (const int*)d_in[3];
    const float* node_w    = (const float*)d_in[4];
    const float* node_b    = (const float*)d_in[5];
    const float* edge_w    = (const float*)d_in[6];
    const float* edge_b    = (const float*)d_in[7];
    const float* eps       = (const float*)d_in[8];
    const float* gin_w1    = (const float*)d_in[9];
    const float* gin_b1    = (const float*)d_in[10];
    const float* gin_w2    = (const float*)d_in[11];
    const float* gin_b2    = (const float*)d_in[12];
    const float* em_w1     = (const float*)d_in[13];
    const float* em_b1     = (const float*)d_in[14];
    const float* em_w2     = (const float*)d_in[15];
    const float* em_b2     = (const float*)d_in[16];
    const float* gru_wih   = (const float*)d_in[17];
    const float* gru_whh   = (const float*)d_in[18];
    const float* gru_bih   = (const float*)d_in[19];
    const float* gru_bhh   = (const float*)d_in[20];
    const float* lstm_wih  = (const float*)d_in[21];
    const float* lstm_whh  = (const float*)d_in[22];
    const float* lstm_bih  = (const float*)d_in[23];
    const float* lstm_bhh  = (const float*)d_in[24];
    const float* fc_w1     = (const float*)d_in[25];
    const float* fc_b1     = (const float*)d_in[26];
    const float* fc_w2     = (const float*)d_in[27];
    const float* fc_b2     = (const float*)d_in[28];
    float* out = (float*)d_out;
    const int* ei_src = edge_index;
    const int* ei_dst = edge_index + TE;

    // ---- workspace layout ----
    char* base = (char*)d_ws;
    size_t off = 0;
    auto alloc = [&](size_t bytes) { void* p = base + off; off += (bytes + 15) & ~size_t(15); return p; };
    bf16*  nodeb = (bf16*)alloc((size_t)TN * TH * 2);   // 25.6 MB
    bf16*  zb    = (bf16*)alloc((size_t)TN * TH * 2);   // 25.6 MB
    bf16*  e1b   = (bf16*)alloc((size_t)TE * TH * 2);   // 51.2 MB (set2set overlay later)
    int*   deg   = (int*)alloc((size_t)TN * 4);
    int*   rowptr= (int*)alloc((size_t)(TN + 1) * 4);
    int*   cur   = (int*)alloc((size_t)TN * 4);
    int*   srcp  = (int*)alloc((size_t)TE * 4);
    int*   einv  = (int*)alloc((size_t)TE * 4);
    int*   bsum  = (int*)alloc(512 * 4);
    int*   bsumx = (int*)alloc(512 * 4);
    int*   gptr  = (int*)alloc((size_t)(TG + 1) * 4);
    bf16*  w6    = (bf16*)alloc(6 * TH * TH * 2);
    bf16*  wgru  = (bf16*)alloc(2 * 384 * TH * 2);
    bf16*  wl    = (bf16*)alloc(512 * 256 * 2);
    if (ws_size < off) return;

    bf16* w_gin1_0 = w6;
    bf16* w_gin1_1 = w6 + 1 * TH * TH;
    bf16* w_gin2_0 = w6 + 2 * TH * TH;
    bf16* w_gin2_1 = w6 + 3 * TH * TH;
    bf16* w_em1    = w6 + 4 * TH * TH;
    bf16* w_em2    = w6 + 5 * TH * TH;
    bf16* w_wih    = wgru;
    bf16* w_whh    = wgru + 384 * TH;

    ushort* sbuf = (ushort*)e1b;                      // [G][256] bf16
    float*  cl   = (float*)(sbuf + (size_t)TG * 256); // [G][128] fp32

    // ---- CSR + gptr ----
    hipMemsetAsync(deg, 0, (size_t)TN * 4, stream);
    hipMemsetAsync(cur, 0, (size_t)TN * 4, stream);
    count_deg<<<(TE + 255) / 256, 256, 0, stream>>>(ei_dst, deg, TE);
    int nb = (TN + 255) / 256;
    scan_block<<<nb, 256, 0, stream>>>(deg, rowptr, bsum, TN);
    scan_bsum<<<1, 512, 0, stream>>>(bsum, bsumx, nb);
    add_off<<<nb, 256, 0, stream>>>(rowptr, bsumx, TN, TE);
    fill_csr<<<(TE + 255) / 256, 256, 0, stream>>>(ei_src, ei_dst, rowptr, cur, srcp, einv, TE);
    build_gptr<<<(TN + 255) / 256, 256, 0, stream>>>(batch, gptr, TN, TG);

    // ---- weights (one merged kernel) ----
    int convTot = 6 * TH * TH + 2 * 384 * TH + 512 * 256;
    convAll<<<(convTot + 255) / 256, 256, 0, stream>>>(
        gin_w1, gin_w2, em_w1, em_w2, gru_wih, gru_whh, lstm_wih, lstm_whh,
        w6, wgru, wl);

    // ---- projections: nodes + e0 in CSR slot order (gather, coalesced write) ----
    proj64<14><<<(TN + 63) / 64, 256, 0, stream>>>(x, node_w, node_b, (ushort*)nodeb, TN);
    proj_gather<<<(TE + 63) / 64, 256, 0, stream>>>(edge_attr, edge_w, edge_b,
                                                    einv, (ushort*)e1b, TE);

    // ---- layer 0: aggregate -> zb; MLP in-place; GRU ----
    aggregate_v8<<<(TN * 16 + 255) / 256, 256, 0, stream>>>(
        (const ushort*)nodeb, (const ushort*)e1b, srcp, rowptr, eps, 0, (ushort*)zb, TN);
    launch_mlp2(zb, w_gin1_0, gin_b1, w_gin2_0, gin_b2, zb, TN, stream);
    gru_fused<<<(TN + 63) / 64, 512, 0, stream>>>(
        (const ushort*)zb, (const ushort*)w_wih, (const ushort*)w_whh,
        gru_bih, gru_bhh, (ushort*)nodeb, TN);

    // ---- edge MLP in-place (slot order preserved), layer 1 ----
    launch_mlp2(e1b, w_em1, em_b1, w_em2, em_b2, e1b, TE, stream);
    aggregate_v8<<<(TN * 16 + 255) / 256, 256, 0, stream>>>(
        (const ushort*)nodeb, (const ushort*)e1b, srcp, rowptr, eps, 1, (ushort*)zb, TN);
    launch_mlp2(zb, w_gin1_1, gin_b1 + TH, w_gin2_1, gin_b2 + TH, zb, TN, stream);
    gru_fused<<<(TN + 63) / 64, 512, 0, stream>>>(
        (const ushort*)zb, (const ushort*)w_wih, (const ushort*)w_whh,
        gru_bih, gru_bhh, (ushort*)nodeb, TN);

    // ---- Set2Set (3 steps) ----
    hipMemsetAsync(sbuf, 0, (size_t)TG * 256 * 2 + (size_t)TG * 128 * 4, stream);
    for (int st = 0; st < 3; ++st) {
        lstm_fused<<<(TG + 15) / 16, 256, 0, stream>>>(
            sbuf, (const ushort*)wl, lstm_bih, lstm_bhh, cl, TG);
        att_fused<<<TG, 256, 0, stream>>>((const ushort*)nodeb, sbuf, gptr);
    }

    // ---- final FC ----
    final_fc<<<TG, 128, 0, stream>>>(sbuf, fc_w1, fc_b1, fc_w2, fc_b2, out);
}

// Round 16
// 555.990 us; speedup vs baseline: 1.0424x; 1.0424x over previous
//
#include <hip/hip_runtime.h>
#include <hip/hip_bf16.h>

constexpr int TN = 100000;   // nodes
constexpr int TE = 200000;   // edges
constexpr int TG = 4000;     // graphs
constexpr int TH = 128;      // hidden

using short8 = __attribute__((ext_vector_type(8))) short;
using f32x4  = __attribute__((ext_vector_type(4))) float;
typedef __hip_bfloat16 bf16;

#define DEVINL __device__ __forceinline__
DEVINL float sigm(float x)  { return 1.f / (1.f + __expf(-x)); }
DEVINL float ftanh(float x) { return 1.f - 2.f / (__expf(2.f * x) + 1.f); }
DEVINL void unpack8(uint4 v, float* f) {
    const ushort* u = (const ushort*)&v;
#pragma unroll
    for (int j = 0; j < 8; ++j) f[j] = __bfloat162float(*(const bf16*)&u[j]);
}

// ================= merged weight conversion =================
__global__ void convAll(const float* __restrict__ g1, const float* __restrict__ g2,
                        const float* __restrict__ e1, const float* __restrict__ e2,
                        const float* __restrict__ gwih, const float* __restrict__ gwhh,
                        const float* __restrict__ lwih, const float* __restrict__ lwhh,
                        bf16* __restrict__ w6, bf16* __restrict__ wgru,
                        bf16* __restrict__ wl) {
    int i = blockIdx.x * 256 + threadIdx.x;
    if (i < 6 * TH * TH) {
        int m = i >> 14, r = i & 16383;
        int n = r >> 7, k = r & 127;
        const float* s = (m == 0) ? g1 : (m == 1) ? g1 + TH * TH
                       : (m == 2) ? g2 : (m == 3) ? g2 + TH * TH
                       : (m == 4) ? e1 : e2;
        w6[i] = __float2bfloat16(s[k * TH + n]);
        return;
    }
    i -= 6 * TH * TH;
    if (i < 2 * 384 * TH) {
        const float* s = (i < 384 * TH) ? gwih : gwhh;
        int r = (i < 384 * TH) ? i : i - 384 * TH;
        wgru[i] = __float2bfloat16(s[r]);
        return;
    }
    i -= 2 * 384 * TH;
    if (i < 512 * 256) {
        int c = i >> 8, k = i & 255;
        float v = (k < 128) ? lwih[c * 256 + k] + lwhh[c * 128 + k] : lwih[c * 256 + k];
        wl[i] = __float2bfloat16(v);
    }
}

// ================= node projection: 64 rows/block ============
template<int K>
__global__ __launch_bounds__(256) void proj64(const float* __restrict__ X,
                                              const float* __restrict__ W,
                                              const float* __restrict__ b,
                                              ushort* __restrict__ out, int M) {
    __shared__ float xs[64][K];
    int tid = threadIdx.x;
    int bm = blockIdx.x * 64;
    for (int i = tid; i < 64 * K; i += 256) {
        int r = i / K, k = i % K;
        xs[r][k] = (bm + r < M) ? X[(size_t)(bm + r) * K + k] : 0.f;
    }
    __syncthreads();
    int rb = tid >> 4, h0 = (tid & 15) * 8;
    float acc[4][8];
#pragma unroll
    for (int j = 0; j < 4; ++j)
#pragma unroll
        for (int c = 0; c < 8; ++c) acc[j][c] = b[h0 + c];
#pragma unroll
    for (int k = 0; k < K; ++k) {
        float4 w0 = *(const float4*)(W + k * TH + h0);
        float4 w1 = *(const float4*)(W + k * TH + h0 + 4);
#pragma unroll
        for (int j = 0; j < 4; ++j) {
            float xv = xs[rb + 16 * j][k];
            acc[j][0] = fmaf(xv, w0.x, acc[j][0]); acc[j][1] = fmaf(xv, w0.y, acc[j][1]);
            acc[j][2] = fmaf(xv, w0.z, acc[j][2]); acc[j][3] = fmaf(xv, w0.w, acc[j][3]);
            acc[j][4] = fmaf(xv, w1.x, acc[j][4]); acc[j][5] = fmaf(xv, w1.y, acc[j][5]);
            acc[j][6] = fmaf(xv, w1.z, acc[j][6]); acc[j][7] = fmaf(xv, w1.w, acc[j][7]);
        }
    }
#pragma unroll
    for (int j = 0; j < 4; ++j) {
        int row = bm + rb + 16 * j;
        if (row >= M) continue;
        ushort o[8];
#pragma unroll
        for (int c = 0; c < 8; ++c) {
            bf16 v = __float2bfloat16(acc[j][c]);
            o[c] = *(ushort*)&v;
        }
        *(uint4*)(out + (size_t)row * TH + h0) = *(uint4*)o;
    }
}

// ===== proj_scatter: K=4 projection with CSR-slot scatter (layer-0 e0) =====
__global__ __launch_bounds__(256) void proj_scatter(
    const float* __restrict__ X, const float* __restrict__ W,
    const float* __restrict__ b, const int* __restrict__ perm,
    ushort* __restrict__ out, int M) {
    __shared__ float xs[64][4];
    int tid = threadIdx.x;
    int bm = blockIdx.x * 64;
    if (tid < 64) {
        float4 a = make_float4(0.f, 0.f, 0.f, 0.f);
        if (bm + tid < M) a = *(const float4*)(X + (size_t)(bm + tid) * 4);
        xs[tid][0] = a.x; xs[tid][1] = a.y; xs[tid][2] = a.z; xs[tid][3] = a.w;
    }
    __syncthreads();
    int rb = tid >> 4, h0 = (tid & 15) * 8;
    float acc[4][8];
#pragma unroll
    for (int j = 0; j < 4; ++j)
#pragma unroll
        for (int c = 0; c < 8; ++c) acc[j][c] = b[h0 + c];
#pragma unroll
    for (int k = 0; k < 4; ++k) {
        float4 w0 = *(const float4*)(W + k * TH + h0);
        float4 w1 = *(const float4*)(W + k * TH + h0 + 4);
#pragma unroll
        for (int j = 0; j < 4; ++j) {
            float xv = xs[rb + 16 * j][k];
            acc[j][0] = fmaf(xv, w0.x, acc[j][0]); acc[j][1] = fmaf(xv, w0.y, acc[j][1]);
            acc[j][2] = fmaf(xv, w0.z, acc[j][2]); acc[j][3] = fmaf(xv, w0.w, acc[j][3]);
            acc[j][4] = fmaf(xv, w1.x, acc[j][4]); acc[j][5] = fmaf(xv, w1.y, acc[j][5]);
            acc[j][6] = fmaf(xv, w1.z, acc[j][6]); acc[j][7] = fmaf(xv, w1.w, acc[j][7]);
        }
    }
#pragma unroll
    for (int j = 0; j < 4; ++j) {
        int row = bm + rb + 16 * j;
        if (row >= M) continue;
        ushort o[8];
#pragma unroll
        for (int c = 0; c < 8; ++c) {
            bf16 v = __float2bfloat16(acc[j][c]);
            o[c] = *(ushort*)&v;
        }
        *(uint4*)(out + (size_t)perm[row] * TH + h0) = *(uint4*)o;
    }
}

// ================= CSR build =================
__global__ void count_deg(const int* __restrict__ ei_dst, int* __restrict__ deg, int En) {
    int e = blockIdx.x * 256 + threadIdx.x;
    if (e < En) atomicAdd(&deg[ei_dst[e]], 1);
}
__global__ void scan_block(const int* __restrict__ deg, int* __restrict__ rowptr,
                           int* __restrict__ bsum, int Nn) {
    __shared__ int sm[256];
    int tid = threadIdx.x;
    int gid = blockIdx.x * 256 + tid;
    int v = (gid < Nn) ? deg[gid] : 0;
    int x = v;
    sm[tid] = x; __syncthreads();
    for (int off = 1; off < 256; off <<= 1) {
        int t = (tid >= off) ? sm[tid - off] : 0;
        __syncthreads();
        x += t; sm[tid] = x;
        __syncthreads();
    }
    if (gid < Nn) rowptr[gid] = x - v;
    if (tid == 255) bsum[blockIdx.x] = x;
}
__global__ void scan_bsum(const int* __restrict__ bsum, int* __restrict__ bsumx, int nb) {
    __shared__ int sm[512];
    int tid = threadIdx.x;
    int v = (tid < nb) ? bsum[tid] : 0;
    int x = v;
    sm[tid] = x; __syncthreads();
    for (int off = 1; off < 512; off <<= 1) {
        int t = (tid >= off) ? sm[tid - off] : 0;
        __syncthreads();
        x += t; sm[tid] = x;
        __syncthreads();
    }
    if (tid < nb) bsumx[tid] = x - v;
}
__global__ void add_off(int* __restrict__ rowptr, const int* __restrict__ bsumx,
                        int Nn, int Etot) {
    int gid = blockIdx.x * 256 + threadIdx.x;
    if (gid < Nn) rowptr[gid] += bsumx[gid >> 8];
    if (gid == 0) rowptr[Nn] = Etot;
}
__global__ void fill_csr(const int* __restrict__ ei_src, const int* __restrict__ ei_dst,
                         const int* __restrict__ rowptr, int* __restrict__ cur,
                         int* __restrict__ srcp, int* __restrict__ epos, int En) {
    int e = blockIdx.x * 256 + threadIdx.x;
    if (e >= En) return;
    int d = ei_dst[e];
    int p = atomicAdd(&cur[d], 1);
    int slot = rowptr[d] + p;
    srcp[slot] = ei_src[e];
    epos[e] = slot;
}
__global__ void build_gptr(const int* __restrict__ batch, int* __restrict__ gptr,
                           int Nn, int Gn) {
    int n = blockIdx.x * 256 + threadIdx.x;
    if (n >= Nn) return;
    int bc = batch[n];
    int bp = (n == 0) ? -1 : batch[n - 1];
    for (int g = bp + 1; g <= bc; ++g) gptr[g] = n;
    if (n == Nn - 1) for (int g = bc + 1; g <= Gn; ++g) gptr[g] = Nn;
}

// ========== aggregation, 16 threads/node, 8 ch/thread, 2-way unroll ==========
__global__ __launch_bounds__(256) void aggregate_v8(
    const ushort* __restrict__ node, const ushort* __restrict__ ef,
    const int* __restrict__ srcp, const int* __restrict__ rowptr,
    const float* __restrict__ eps, int l, ushort* __restrict__ zb, int Nn) {
    int t = blockIdx.x * 256 + threadIdx.x;
    int n = t >> 4;
    if (n >= Nn) return;
    int c8 = (t & 15) * 8;
    float se = 1.f + eps[l];
    float acc[8];
    uint4 nv = *(const uint4*)(node + (size_t)n * TH + c8);
    unpack8(nv, acc);
#pragma unroll
    for (int j = 0; j < 8; ++j) acc[j] *= se;
    int s0 = rowptr[n], s1 = rowptr[n + 1];
    int i = s0;
    for (; i + 1 < s1; i += 2) {
        int sa = srcp[i], sb = srcp[i + 1];
        uint4 av0 = *(const uint4*)(node + (size_t)sa * TH + c8);
        uint4 bv0 = *(const uint4*)(ef + (size_t)i * TH + c8);
        uint4 av1 = *(const uint4*)(node + (size_t)sb * TH + c8);
        uint4 bv1 = *(const uint4*)(ef + (size_t)(i + 1) * TH + c8);
        float a0[8], b0[8], a1[8], b1[8];
        unpack8(av0, a0); unpack8(bv0, b0);
        unpack8(av1, a1); unpack8(bv1, b1);
#pragma unroll
        for (int j = 0; j < 8; ++j)
            acc[j] += fmaxf(a0[j] + b0[j], 0.f) + fmaxf(a1[j] + b1[j], 0.f);
    }
    if (i < s1) {
        int sa = srcp[i];
        uint4 av = *(const uint4*)(node + (size_t)sa * TH + c8);
        uint4 bv = *(const uint4*)(ef + (size_t)i * TH + c8);
        float af[8], bf[8];
        unpack8(av, af); unpack8(bv, bf);
#pragma unroll
        for (int j = 0; j < 8; ++j) acc[j] += fmaxf(af[j] + bf[j], 0.f);
    }
    ushort o[8];
#pragma unroll
    for (int j = 0; j < 8; ++j) {
        bf16 v = __float2bfloat16(acc[j]);
        o[j] = *(ushort*)&v;
    }
    *(uint4*)(zb + (size_t)n * TH + c8) = *(uint4*)o;
}

// ================= fused 2-layer MLP (weights preloaded to registers) =================
__global__ __launch_bounds__(256) void mlp2_fused(
    const ushort* __restrict__ A, const ushort* __restrict__ W1t,
    const float* __restrict__ b1, const ushort* __restrict__ W2t,
    const float* __restrict__ b2, ushort* __restrict__ C, int M)
{
    __shared__ ushort As[128 * 128];
    __shared__ ushort Ts[128 * 128];
    const int tid = threadIdx.x;
    const int bm = blockIdx.x * 128;
    const int lane = tid & 63, w = tid >> 6;
    const int lr = lane & 15, lq = lane >> 4;
    const int wm = (w & 1) * 64, wn = (w >> 1) * 64;
    short8 wf[4][4];
#pragma unroll
    for (int ni = 0; ni < 4; ++ni)
#pragma unroll
        for (int ks = 0; ks < 4; ++ks)
            wf[ni][ks] = *(const short8*)(W1t + (size_t)(wn + ni * 16 + lr) * 128 + ks * 32 + lq * 8);
#pragma unroll
    for (int p = 0; p < 8; ++p) {
        int ch = p * 256 + tid;
        int r = ch >> 4, c = ch & 15;
        int row = bm + r;
        uint4 v = make_uint4(0u, 0u, 0u, 0u);
        if (row < M) v = *(const uint4*)(A + (size_t)row * 128 + c * 8);
        *(uint4*)(&As[r * 128 + ((c ^ (r & 15)) * 8)]) = v;
    }
    __syncthreads();
    {
        f32x4 acc[4][4] = {};
#pragma unroll
        for (int ks = 0; ks < 4; ++ks) {
            int cb = ks * 4 + lq;
            short8 af[4];
#pragma unroll
            for (int mi = 0; mi < 4; ++mi)
                af[mi] = *(const short8*)(&As[(wm + mi * 16 + lr) * 128 + ((cb ^ lr) * 8)]);
#pragma unroll
            for (int mi = 0; mi < 4; ++mi)
#pragma unroll
                for (int ni = 0; ni < 4; ++ni)
                    acc[mi][ni] = __builtin_amdgcn_mfma_f32_16x16x32_bf16(af[mi], wf[ni][ks], acc[mi][ni], 0, 0, 0);
        }
#pragma unroll
        for (int mi = 0; mi < 4; ++mi)
#pragma unroll
            for (int reg = 0; reg < 4; ++reg) {
                int row = wm + mi * 16 + lq * 4 + reg;
#pragma unroll
                for (int ni = 0; ni < 4; ++ni) {
                    int col = wn + ni * 16 + lr;
                    float v = fmaxf(acc[mi][ni][reg] + b1[col], 0.f);
                    bf16 bv = __float2bfloat16(v);
                    Ts[row * 128 + (((col >> 3) ^ (row & 15)) * 8) + (col & 7)] = *(ushort*)&bv;
                }
            }
    }
#pragma unroll
    for (int ni = 0; ni < 4; ++ni)
#pragma unroll
        for (int ks = 0; ks < 4; ++ks)
            wf[ni][ks] = *(const short8*)(W2t + (size_t)(wn + ni * 16 + lr) * 128 + ks * 32 + lq * 8);
    __syncthreads();
    {
        f32x4 acc[4][4] = {};
#pragma unroll
        for (int ks = 0; ks < 4; ++ks) {
            int cb = ks * 4 + lq;
            short8 af[4];
#pragma unroll
            for (int mi = 0; mi < 4; ++mi)
                af[mi] = *(const short8*)(&Ts[(wm + mi * 16 + lr) * 128 + ((cb ^ lr) * 8)]);
#pragma unroll
            for (int mi = 0; mi < 4; ++mi)
#pragma unroll
                for (int ni = 0; ni < 4; ++ni)
                    acc[mi][ni] = __builtin_amdgcn_mfma_f32_16x16x32_bf16(af[mi], wf[ni][ks], acc[mi][ni], 0, 0, 0);
        }
#pragma unroll
        for (int mi = 0; mi < 4; ++mi)
#pragma unroll
            for (int reg = 0; reg < 4; ++reg) {
                int row = bm + wm + mi * 16 + lq * 4 + reg;
                if (row >= M) continue;
#pragma unroll
                for (int ni = 0; ni < 4; ++ni) {
                    int col = wn + ni * 16 + lr;
                    bf16 bv = __float2bfloat16(acc[mi][ni][reg] + b2[col]);
                    C[(size_t)row * 128 + col] = *(ushort*)&bv;
                }
            }
    }
}

// ===== fused GRU: 512 thr, 64 rows/block, 16 cols/wave, 96 MFMA/wave =====
__global__ __launch_bounds__(512, 4) void gru_fused(
    const ushort* __restrict__ mfeat, const ushort* __restrict__ wih,
    const ushort* __restrict__ whh, const float* __restrict__ bih,
    const float* __restrict__ bhh, ushort* __restrict__ node, int Nn)
{
    __shared__ ushort Ms[64 * 128];
    __shared__ ushort Hs[64 * 128];
    const int tid = threadIdx.x;
    const int bm = blockIdx.x * 64;
#pragma unroll
    for (int p = 0; p < 4; ++p) {
        int ch = p * 512 + tid;
        bool isH = ch >= 1024;
        int r = (ch >> 4) & 63, c = ch & 15;
        int row = bm + r;
        uint4 v = make_uint4(0u, 0u, 0u, 0u);
        if (row < Nn) v = *(const uint4*)((isH ? node : mfeat) + (size_t)row * 128 + c * 8);
        ushort* dst = isH ? Hs : Ms;
        *(uint4*)(&dst[r * 128 + ((c ^ (r & 15)) * 8)]) = v;
    }
    __syncthreads();
    const int lane = tid & 63, w = tid >> 6;
    const int lr = lane & 15, lq = lane >> 4;
    const int col = w * 16 + lr;
    f32x4 aR[4] = {}, aZ[4] = {}, aN[4] = {}, aH[4] = {};
#pragma unroll
    for (int ks = 0; ks < 4; ++ks) {
        int koff = ks * 32 + lq * 8;
        short8 wv0 = *(const short8*)(wih + (size_t)col * 128 + koff);
        short8 wv1 = *(const short8*)(wih + (size_t)(128 + col) * 128 + koff);
        short8 wv2 = *(const short8*)(wih + (size_t)(256 + col) * 128 + koff);
        short8 wv3 = *(const short8*)(whh + (size_t)col * 128 + koff);
        short8 wv4 = *(const short8*)(whh + (size_t)(128 + col) * 128 + koff);
        short8 wv5 = *(const short8*)(whh + (size_t)(256 + col) * 128 + koff);
        int cb = ks * 4 + lq;
#pragma unroll
        for (int rt = 0; rt < 4; ++rt) {
            int off = (rt * 16 + lr) * 128 + ((cb ^ lr) * 8);
            short8 am = *(const short8*)(&Ms[off]);
            short8 ah = *(const short8*)(&Hs[off]);
            aR[rt] = __builtin_amdgcn_mfma_f32_16x16x32_bf16(am, wv0, aR[rt], 0, 0, 0);
            aR[rt] = __builtin_amdgcn_mfma_f32_16x16x32_bf16(ah, wv3, aR[rt], 0, 0, 0);
            aZ[rt] = __builtin_amdgcn_mfma_f32_16x16x32_bf16(am, wv1, aZ[rt], 0, 0, 0);
            aZ[rt] = __builtin_amdgcn_mfma_f32_16x16x32_bf16(ah, wv4, aZ[rt], 0, 0, 0);
            aN[rt] = __builtin_amdgcn_mfma_f32_16x16x32_bf16(am, wv2, aN[rt], 0, 0, 0);
            aH[rt] = __builtin_amdgcn_mfma_f32_16x16x32_bf16(ah, wv5, aH[rt], 0, 0, 0);
        }
    }
    {
        int h = col;
        float br = bih[h] + bhh[h];
        float bz = bih[128 + h] + bhh[128 + h];
        float bin = bih[256 + h], bhn = bhh[256 + h];
#pragma unroll
        for (int rt = 0; rt < 4; ++rt)
#pragma unroll
            for (int reg = 0; reg < 4; ++reg) {
                int lrow = rt * 16 + lq * 4 + reg;
                int row = bm + lrow;
                if (row >= Nn) continue;
                float r = sigm(aR[rt][reg] + br);
                float z = sigm(aZ[rt][reg] + bz);
                float n = ftanh(aN[rt][reg] + bin + r * (aH[rt][reg] + bhn));
                int hofs = lrow * 128 + (((h >> 3) ^ (lrow & 15)) * 8) + (h & 7);
                float hold = __bfloat162float(*(const bf16*)&Hs[hofs]);
                bf16 hv = __float2bfloat16((1.f - z) * n + z * hold);
                node[(size_t)row * 128 + h] = *(ushort*)&hv;
            }
    }
}

// ================= fused LSTM step (16 graphs/block) =================
__global__ __launch_bounds__(256) void lstm_fused(
    ushort* __restrict__ s, const ushort* __restrict__ Wl,
    const float* __restrict__ bih, const float* __restrict__ bhh,
    float* __restrict__ cl, int Gn)
{
    __shared__ ushort Ss[16 * 256];
    const int tid = threadIdx.x;
    const int bm = blockIdx.x * 16;
#pragma unroll
    for (int p = 0; p < 2; ++p) {
        int ch = p * 256 + tid;
        int r = ch >> 5, c = ch & 31;
        int row = bm + r;
        uint4 v = make_uint4(0u, 0u, 0u, 0u);
        if (row < Gn) v = *(const uint4*)(s + (size_t)row * 256 + c * 8);
        *(uint4*)(&Ss[r * 256 + ((c ^ (r & 15)) * 8)]) = v;
    }
    __syncthreads();
    const int lane = tid & 63, w = tid >> 6;
    const int lr = lane & 15, lq = lane >> 4;
    f32x4 acc[4][2] = {};
#pragma unroll
    for (int ks = 0; ks < 8; ++ks) {
        int cb = ks * 4 + lq;
        short8 am = *(const short8*)(&Ss[lr * 256 + ((cb ^ lr) * 8)]);
        int koff = ks * 32 + lq * 8;
#pragma unroll
        for (int g = 0; g < 4; ++g)
#pragma unroll
            for (int sub = 0; sub < 2; ++sub) {
                int col = g * 128 + w * 32 + sub * 16 + lr;
                short8 bf = *(const short8*)(Wl + (size_t)col * 256 + koff);
                acc[g][sub] = __builtin_amdgcn_mfma_f32_16x16x32_bf16(am, bf, acc[g][sub], 0, 0, 0);
            }
    }
#pragma unroll
    for (int sub = 0; sub < 2; ++sub) {
        int h = w * 32 + sub * 16 + lr;
        float bi = bih[h] + bhh[h];
        float bff = bih[128 + h] + bhh[128 + h];
        float bg = bih[256 + h] + bhh[256 + h];
        float bo = bih[384 + h] + bhh[384 + h];
#pragma unroll
        for (int reg = 0; reg < 4; ++reg) {
            int row = bm + lq * 4 + reg;
            if (row >= Gn) continue;
            float iv = sigm(acc[0][sub][reg] + bi);
            float fv = sigm(acc[1][sub][reg] + bff);
            float gv = ftanh(acc[2][sub][reg] + bg);
            float ov = sigm(acc[3][sub][reg] + bo);
            float c = fv * cl[(size_t)row * 128 + h] + iv * gv;
            cl[(size_t)row * 128 + h] = c;
            bf16 hv = __float2bfloat16(ov * ftanh(c));
            s[(size_t)row * 256 + h] = *(ushort*)&hv;
        }
    }
}

// ================= fused per-graph attention (vectorized, no reg cache) =========
__global__ __launch_bounds__(256) void att_fused(
    const ushort* __restrict__ node, ushort* __restrict__ s,
    const int* __restrict__ gptr)
{
    __shared__ float q[128];
    __shared__ float es[512];
    __shared__ float red[8];
    __shared__ float part[16][128];
    int g = blockIdx.x;
    int tid = threadIdx.x, lane = tid & 63, wid = tid >> 6;
    int n0 = gptr[g], n1 = gptr[g + 1];
    int cnt = n1 - n0; if (cnt > 512) cnt = 512;
    if (tid < 128) q[tid] = __bfloat162float(((const bf16*)s)[(size_t)g * 256 + tid]);
    __syncthreads();
    int gr = tid >> 4, c8 = (tid & 15) * 8;
    for (int i0 = 0; i0 < cnt; i0 += 16) {
        int i = i0 + gr;
        float p = 0.f;
        if (i < cnt) {
            uint4 v = *(const uint4*)(node + (size_t)(n0 + i) * TH + c8);
            float f[8]; unpack8(v, f);
#pragma unroll
            for (int j = 0; j < 8; ++j) p = fmaf(f[j], q[c8 + j], p);
        }
        p += __shfl_down(p, 8, 16);
        p += __shfl_down(p, 4, 16);
        p += __shfl_down(p, 2, 16);
        p += __shfl_down(p, 1, 16);
        if ((tid & 15) == 0 && i < cnt) es[i] = p;
    }
    __syncthreads();
    float m = -1e30f;
    for (int i = tid; i < cnt; i += 256) m = fmaxf(m, es[i]);
    for (int off = 32; off; off >>= 1) m = fmaxf(m, __shfl_down(m, off));
    if (lane == 0) red[wid] = m;
    __syncthreads();
    m = fmaxf(fmaxf(red[0], red[1]), fmaxf(red[2], red[3]));
    float sm = 0.f;
    for (int i = tid; i < cnt; i += 256) { float ex = __expf(es[i] - m); es[i] = ex; sm += ex; }
    for (int off = 32; off; off >>= 1) sm += __shfl_down(sm, off);
    if (lane == 0) red[4 + wid] = sm;
    __syncthreads();
    sm = red[4] + red[5] + red[6] + red[7];
    float inv = 1.f / fmaxf(sm, 1e-9f);
    float racc[8] = {};
    for (int i = gr; i < cnt; i += 16) {
        uint4 v = *(const uint4*)(node + (size_t)(n0 + i) * TH + c8);
        float f[8]; unpack8(v, f);
        float a = es[i];
#pragma unroll
        for (int j = 0; j < 8; ++j) racc[j] = fmaf(a, f[j], racc[j]);
    }
#pragma unroll
    for (int j = 0; j < 8; ++j) part[gr][c8 + j] = racc[j];
    __syncthreads();
    if (tid < 128) {
        float r = 0.f;
#pragma unroll
        for (int k = 0; k < 16; ++k) r += part[k][tid];
        bf16 rv = __float2bfloat16(r * inv);
        s[(size_t)g * 256 + 128 + tid] = *(ushort*)&rv;
    }
}

// ================= final FC =================
__global__ __launch_bounds__(128) void final_fc(const ushort* __restrict__ s,
                                                const float* __restrict__ w1,
                                                const float* __restrict__ b1,
                                                const float* __restrict__ w2,
                                                const float* __restrict__ b2,
                                                float* __restrict__ out) {
    __shared__ float q[256];
    __shared__ float red[2];
    int g = blockIdx.x, t = threadIdx.x;
    q[t] = __bfloat162float(((const bf16*)s)[(size_t)g * 256 + t]);
    q[t + 128] = __bfloat162float(((const bf16*)s)[(size_t)g * 256 + 128 + t]);
    __syncthreads();
    float acc = b1[t];
    for (int k = 0; k < 256; ++k) acc = fmaf(q[k], w1[k * TH + t], acc);
    acc = fmaxf(acc, 0.f);
    float p = acc * w2[t];
    for (int off = 32; off; off >>= 1) p += __shfl_down(p, off);
    if ((t & 63) == 0) red[t >> 6] = p;
    __syncthreads();
    if (t == 0) out[g] = red[0] + red[1] + b2[0];
}

// ---------------------------------------------------------------------------
static void launch_mlp2(const void* A, const bf16* W1t, const float* b1,
                        const bf16* W2t, const float* b2, void* C, int M, hipStream_t s) {
    hipLaunchKernelGGL(mlp2_fused, dim3((M + 127) / 128), dim3(256), 0, s,
                       (const ushort*)A, (const ushort*)W1t, b1, (const ushort*)W2t, b2,
                       (ushort*)C, M);
}

extern "C" void kernel_launch(void* const* d_in, const int* in_sizes, int n_in,
                              void* d_out, int out_size, void* d_ws, size_t ws_size,
                              hipStream_t stream) {
    const float* x         = (const float*)d_in[0];
    const float* edge_attr = (const float*)d_in[1];
    const int*   edge_index= (const int*)d_in[2];
    const int*   batch     = (const int*)d_in[3];
    const float* node_w    = (const float*)d_in[4];
    const float* node_b    = (const float*)d_in[5];
    const float* edge_w    = (const float*)d_in[6];
    const float* edge_b    = (const float*)d_in[7];
    const float* eps       = (const float*)d_in[8];
    const float* gin_w1    = (const float*)d_in[9];
    const float* gin_b1    = (const float*)d_in[10];
    const float* gin_w2    = (const float*)d_in[11];
    const float* gin_b2    = (const float*)d_in[12];
    const float* em_w1     = (const float*)d_in[13];
    const float* em_b1     = (const float*)d_in[14];
    const float* em_w2     = (const float*)d_in[15];
    const float* em_b2     = (const float*)d_in[16];
    const float* gru_wih   = (const float*)d_in[17];
    const float* gru_whh   = (const float*)d_in[18];
    const float* gru_bih   = (const float*)d_in[19];
    const float* gru_bhh   = (const float*)d_in[20];
    const float* lstm_wih  = (const float*)d_in[21];
    const float* lstm_whh  = (const float*)d_in[22];
    const float* lstm_bih  = (const float*)d_in[23];
    const float* lstm_bhh  = (const float*)d_in[24];
    const float* fc_w1     = (const float*)d_in[25];
    const float* fc_b1     = (const float*)d_in[26];
    const float* fc_w2     = (const float*)d_in[27];
    const float* fc_b2     = (const float*)d_in[28];
    float* out = (float*)d_out;
    const int* ei_src = edge_index;
    const int* ei_dst = edge_index + TE;

    // ---- workspace layout ----
    char* base = (char*)d_ws;
    size_t off = 0;
    auto alloc = [&](size_t bytes) { void* p = base + off; off += (bytes + 15) & ~size_t(15); return p; };
    bf16*  nodeb = (bf16*)alloc((size_t)TN * TH * 2);   // 25.6 MB
    bf16*  zb    = (bf16*)alloc((size_t)TN * TH * 2);   // 25.6 MB
    bf16*  e1b   = (bf16*)alloc((size_t)TE * TH * 2);   // 51.2 MB (set2set overlay later)
    int*   deg   = (int*)alloc((size_t)TN * 4);
    int*   rowptr= (int*)alloc((size_t)(TN + 1) * 4);
    int*   cur   = (int*)alloc((size_t)TN * 4);
    int*   srcp  = (int*)alloc((size_t)TE * 4);
    int*   epos  = (int*)alloc((size_t)TE * 4);
    int*   bsum  = (int*)alloc(512 * 4);
    int*   bsumx = (int*)alloc(512 * 4);
    int*   gptr  = (int*)alloc((size_t)(TG + 1) * 4);
    bf16*  w6    = (bf16*)alloc(6 * TH * TH * 2);
    bf16*  wgru  = (bf16*)alloc(2 * 384 * TH * 2);
    bf16*  wl    = (bf16*)alloc(512 * 256 * 2);
    if (ws_size < off) return;

    bf16* w_gin1_0 = w6;
    bf16* w_gin1_1 = w6 + 1 * TH * TH;
    bf16* w_gin2_0 = w6 + 2 * TH * TH;
    bf16* w_gin2_1 = w6 + 3 * TH * TH;
    bf16* w_em1    = w6 + 4 * TH * TH;
    bf16* w_em2    = w6 + 5 * TH * TH;
    bf16* w_wih    = wgru;
    bf16* w_whh    = wgru + 384 * TH;

    ushort* sbuf = (ushort*)e1b;                      // [G][256] bf16
    float*  cl   = (float*)(sbuf + (size_t)TG * 256); // [G][128] fp32

    // ---- CSR + gptr ----
    hipMemsetAsync(deg, 0, (size_t)TN * 4, stream);
    hipMemsetAsync(cur, 0, (size_t)TN * 4, stream);
    count_deg<<<(TE + 255) / 256, 256, 0, stream>>>(ei_dst, deg, TE);
    int nb = (TN + 255) / 256;
    scan_block<<<nb, 256, 0, stream>>>(deg, rowptr, bsum, TN);
    scan_bsum<<<1, 512, 0, stream>>>(bsum, bsumx, nb);
    add_off<<<nb, 256, 0, stream>>>(rowptr, bsumx, TN, TE);
    fill_csr<<<(TE + 255) / 256, 256, 0, stream>>>(ei_src, ei_dst, rowptr, cur, srcp, epos, TE);
    build_gptr<<<(TN + 255) / 256, 256, 0, stream>>>(batch, gptr, TN, TG);

    // ---- weights (one merged kernel) ----
    int convTot = 6 * TH * TH + 2 * 384 * TH + 512 * 256;
    convAll<<<(convTot + 255) / 256, 256, 0, stream>>>(
        gin_w1, gin_w2, em_w1, em_w2, gru_wih, gru_whh, lstm_wih, lstm_whh,
        w6, wgru, wl);

    // ---- projections (edges scattered into CSR slot order) ----
    proj64<14><<<(TN + 63) / 64, 256, 0, stream>>>(x, node_w, node_b, (ushort*)nodeb, TN);
    proj_scatter<<<(TE + 63) / 64, 256, 0, stream>>>(edge_attr, edge_w, edge_b,
                                                     epos, (ushort*)e1b, TE);

    // ---- layer 0: aggregate -> zb; MLP in-place; GRU ----
    aggregate_v8<<<(TN * 16 + 255) / 256, 256, 0, stream>>>(
        (const ushort*)nodeb, (const ushort*)e1b, srcp, rowptr, eps, 0, (ushort*)zb, TN);
    launch_mlp2(zb, w_gin1_0, gin_b1, w_gin2_0, gin_b2, zb, TN, stream);
    gru_fused<<<(TN + 63) / 64, 512, 0, stream>>>(
        (const ushort*)zb, (const ushort*)w_wih, (const ushort*)w_whh,
        gru_bih, gru_bhh, (ushort*)nodeb, TN);

    // ---- edge MLP in-place (slot order preserved), layer 1 ----
    launch_mlp2(e1b, w_em1, em_b1, w_em2, em_b2, e1b, TE, stream);
    aggregate_v8<<<(TN * 16 + 255) / 256, 256, 0, stream>>>(
        (const ushort*)nodeb, (const ushort*)e1b, srcp, rowptr, eps, 1, (ushort*)zb, TN);
    launch_mlp2(zb, w_gin1_1, gin_b1 + TH, w_gin2_1, gin_b2 + TH, zb, TN, stream);
    gru_fused<<<(TN + 63) / 64, 512, 0, stream>>>(
        (const ushort*)zb, (const ushort*)w_wih, (const ushort*)w_whh,
        gru_bih, gru_bhh, (ushort*)nodeb, TN);

    // ---- Set2Set (3 steps) ----
    hipMemsetAsync(sbuf, 0, (size_t)TG * 256 * 2 + (size_t)TG * 128 * 4, stream);
    for (int st = 0; st < 3; ++st) {
        lstm_fused<<<(TG + 15) / 16, 256, 0, stream>>>(
            sbuf, (const ushort*)wl, lstm_bih, lstm_bhh, cl, TG);
        att_fused<<<TG, 256, 0, stream>>>((const ushort*)nodeb, sbuf, gptr);
    }

    // ---- final FC ----
    final_fc<<<TG, 128, 0, stream>>>(sbuf, fc_w1, fc_b1, fc_w2, fc_b2, out);
}